// Round 4
// baseline (299.675 us; speedup 1.0000x reference)
//
#include <hip/hip_runtime.h>
#include <math.h>

// out = softmax(Q @ M^T / 0.02) @ M ; B=8, L=2048, D=1024, fp32.
// Round 4: (a) coalesced LDS-transpose convert kernel;
//          (b) LDS-staged double-buffered MFMA K-loop (global_load_lds w=16),
//              removing redundant A fetches and latency-bound L2 reads.
// Exact fp32 refinement epilogue unchanged. Fallback (small ws) = round-2 style.

typedef __bf16 bf16x8 __attribute__((ext_vector_type(8)));
typedef float  f32x4  __attribute__((ext_vector_type(4)));
typedef float  f32x16 __attribute__((ext_vector_type(16)));

constexpr int   B_ = 8;
constexpr int   L_ = 2048;
constexpr int   D_ = 1024;
constexpr float SCALE  = 50.0f;   // 1/0.02
constexpr float MARGIN = 1.2f;    // dot units (=60 logit units)
constexpr int   BQ   = 64;
constexpr int   RCAP = 32;        // per-row survivor capacity (expect ~1-3)

// ws: bf16 T[2][8][64 dblk][2048 r][16 e]
constexpr size_t WS_T_ELEMS = (size_t)8 * 64 * 2048 * 16;
constexpr size_t WS_NEED    = 2 * WS_T_ELEMS * 2;   // 64 MiB

static __device__ __forceinline__ unsigned short f2bf(float x) {
    unsigned u = __builtin_bit_cast(unsigned, x);
    u += 0x7FFFu + ((u >> 16) & 1u);   // RNE
    return (unsigned short)(u >> 16);
}

typedef const unsigned int __attribute__((address_space(1)))* gas_t;
typedef unsigned int __attribute__((address_space(3)))*       las_t;
static __device__ __forceinline__ void async_cp16(const void* g, void* l) {
    __builtin_amdgcn_global_load_lds((gas_t)g, (las_t)l, 16, 0, 0);
}

// ---------------- convert: fp32 [b][r][d] -> bf16 tiled [b][dblk][r][16] ----
// Block tile: 64 rows x 256 d. Coalesced reads, LDS transpose, coalesced writes.
constexpr int CPR = 24;               // LDS row stride (elems)
constexpr int CPL = 64 * CPR + 8;     // plane stride = 1544 elems (bank-spread)

__global__ __launch_bounds__(256) void convert2(
    const float* __restrict__ Q, const float* __restrict__ M,
    __bf16* __restrict__ ws)
{
    __shared__ __bf16 t[16 * CPL];    // ~49 KB

    const int tt = blockIdx.y;
    const int x  = blockIdx.x;        // b(3) | rt(5) | dt(2)
    const int b  = x >> 7;
    const int rt = (x >> 2) & 31;
    const int dt = x & 3;
    const int r0 = rt * 64, d0 = dt * 256;

    const float* src = (tt ? M : Q) + (size_t)b * L_ * D_;
    __bf16* dst = ws + ((size_t)tt * 8 + b) * (64ull * 2048 * 16);

    #pragma unroll
    for (int k = 0; k < 16; ++k) {
        int idx = k * 256 + threadIdx.x;
        int row = idx >> 6, c4 = idx & 63;
        float4 v = *(const float4*)(src + (size_t)(r0 + row) * D_ + d0 + c4 * 4);
        union { unsigned short h[4]; uint2 u; } o;
        o.h[0] = f2bf(v.x); o.h[1] = f2bf(v.y);
        o.h[2] = f2bf(v.z); o.h[3] = f2bf(v.w);
        *(uint2*)&t[(c4 >> 2) * CPL + row * CPR + (c4 & 3) * 4] = o.u;
    }
    __syncthreads();
    #pragma unroll
    for (int k = 0; k < 4; ++k) {
        int idx  = k * 256 + threadIdx.x;
        int dblk = idx >> 6, row = idx & 63;
        const __bf16* sp = &t[dblk * CPL + row * CPR];
        __bf16* dp = dst + ((size_t)(dt * 16 + dblk) * 2048 + r0 + row) * 16;
        *(uint4*)dp       = *(const uint4*)sp;
        *((uint4*)dp + 1) = *((const uint4*)sp + 1);
    }
}

// ---------------- main kernel -----------------------------------------------
// Stage (per 32-d step): A 64x32 (4 KB) + B 1024x32 (64 KB) bf16, dbuf.
// Chunk map (16B units): A0 [0,128) A1 [128,256) B0 [256,2304) B1 [2304,4352)
__global__ __launch_bounds__(512, 2) void attn_main(
    const float* __restrict__ Q, const float* __restrict__ M,
    const __bf16* __restrict__ ws, float* __restrict__ Out)
{
    __shared__ __bf16 sbuf[2][34816];     // 2 x 68 KB = 136 KB
    __shared__ float  wmax[8][BQ];        // 2 KB
    __shared__ float  rm_s[BQ], thr_s[BQ];
    __shared__ int    rowcnt[BQ];
    __shared__ int    rowlist[BQ][RCAP];  // 8 KB
    __shared__ float  rowval[BQ][RCAP];   // 8 KB

    const int b    = blockIdx.x & 7;      // batch per XCD for L2 locality
    const int qt   = blockIdx.x >> 3;
    const int q0   = qt * BQ;
    const int tid  = threadIdx.x;
    const int w    = tid >> 6;
    const int lane = tid & 63;
    const int ln31 = lane & 31;
    const int h2   = lane >> 5;

    const __bf16* qws = ws + (size_t)b * (64ull * 2048 * 16);
    const __bf16* mws = ws + ((size_t)8 + b) * (64ull * 2048 * 16);
    const float*  Qb  = Q + ((size_t)b * L_ + q0) * D_;
    const float*  Mb  = M + (size_t)b * L_ * D_;

    // stage issue: s in [0,64); kt = s>>5, dq = s&31 (2 dblks per stage)
    auto stage_issue = [&](int s, __bf16* buf) {
        const int kt = s >> 5, dq = s & 31;
        const __bf16* sA0 = qws + ((size_t)(dq * 2 + 0) * 2048 + q0) * 16;
        const __bf16* sA1 = qws + ((size_t)(dq * 2 + 1) * 2048 + q0) * 16;
        const __bf16* sB0 = mws + ((size_t)(dq * 2 + 0) * 2048 + kt * 1024) * 16;
        const __bf16* sB1 = mws + ((size_t)(dq * 2 + 1) * 2048 + kt * 1024) * 16;
        #pragma unroll
        for (int i = 0; i < 8; ++i) {
            const int cb = i * 512 + w * 64;           // wave-uniform
            const __bf16* src; int rs;
            if (cb < 128)       { src = sA0; rs = 0; }
            else if (cb < 256)  { src = sA1; rs = 128; }
            else if (cb < 2304) { src = sB0; rs = 256; }
            else                { src = sB1; rs = 2304; }
            async_cp16(src + (size_t)(cb - rs + lane) * 8, buf + (size_t)cb * 8);
        }
        if (tid < 256) {                               // tail: 256 chunks of B1
            const int cb = 4096 + w * 64;
            async_cp16(sB1 + (size_t)(cb - 2304 + lane) * 8, buf + (size_t)cb * 8);
        }
    };

    stage_issue(0, sbuf[0]);
    if (tid < BQ) { rm_s[tid] = -INFINITY; rowcnt[tid] = 0; }
    __syncthreads();   // drains stage 0

    #pragma unroll 1
    for (int kt = 0; kt < 2; ++kt) {
        const int nb = kt * 1024 + w * 128;

        f32x16 acc[2][4];
        #pragma unroll
        for (int i = 0; i < 2; ++i)
            #pragma unroll
            for (int j = 0; j < 4; ++j)
                #pragma unroll
                for (int e = 0; e < 16; ++e) acc[i][j][e] = 0.f;

        auto do_stage = [&](int s, const __bf16* cur, __bf16* nxt) {
            if (s < 63) stage_issue(s + 1, nxt);
            bf16x8 af[2][2], bfr[2][4];
            #pragma unroll
            for (int dl = 0; dl < 2; ++dl) {
                #pragma unroll
                for (int i = 0; i < 2; ++i)
                    af[dl][i] = *(const bf16x8*)(cur + dl * 1024 +
                                    (i * 32 + ln31) * 16 + h2 * 8);
                #pragma unroll
                for (int j = 0; j < 4; ++j)
                    bfr[dl][j] = *(const bf16x8*)(cur + 2048 + dl * 16384 +
                                    (w * 128 + j * 32 + ln31) * 16 + h2 * 8);
            }
            #pragma unroll
            for (int dl = 0; dl < 2; ++dl)
                #pragma unroll
                for (int i = 0; i < 2; ++i)
                    #pragma unroll
                    for (int j = 0; j < 4; ++j)
                        acc[i][j] = __builtin_amdgcn_mfma_f32_32x32x16_bf16(
                            af[dl][i], bfr[dl][j], acc[i][j], 0, 0, 0);
            __syncthreads();   // vmcnt(0) drain of s+1 prefetch + barrier
        };

        #pragma unroll 1
        for (int dq = 0; dq < 32; dq += 2) {
            const int s = kt * 32 + dq;
            do_stage(s,     sbuf[0], sbuf[1]);
            do_stage(s + 1, sbuf[1], sbuf[0]);
        }

        // ---- block-wide running rowmax ----
        float lm[2][16];
        #pragma unroll
        for (int i = 0; i < 2; ++i)
            #pragma unroll
            for (int g = 0; g < 16; ++g)
                lm[i][g] = fmaxf(fmaxf(acc[i][0][g], acc[i][1][g]),
                                 fmaxf(acc[i][2][g], acc[i][3][g]));
        #pragma unroll
        for (int off = 1; off <= 16; off <<= 1)
            #pragma unroll
            for (int i = 0; i < 2; ++i)
                #pragma unroll
                for (int g = 0; g < 16; ++g)
                    lm[i][g] = fmaxf(lm[i][g], __shfl_xor(lm[i][g], off, 64));
        if (ln31 == 0) {
            #pragma unroll
            for (int i = 0; i < 2; ++i)
                #pragma unroll
                for (int g = 0; g < 16; ++g)
                    wmax[w][i * 32 + (g & 3) + 8 * (g >> 2) + 4 * h2] = lm[i][g];
        }
        __syncthreads();
        if (tid < BQ) {
            float m = wmax[0][tid];
            #pragma unroll
            for (int ww = 1; ww < 8; ++ww) m = fmaxf(m, wmax[ww][tid]);
            m = fmaxf(m, rm_s[tid]);
            rm_s[tid] = m;
            thr_s[tid] = m - MARGIN;
        }
        __syncthreads();

        // ---- survivor push ----
        #pragma unroll
        for (int i = 0; i < 2; ++i)
            #pragma unroll
            for (int g = 0; g < 16; ++g) {
                const int rl = i * 32 + (g & 3) + 8 * (g >> 2) + 4 * h2;
                const float thr = thr_s[rl];
                #pragma unroll
                for (int j = 0; j < 4; ++j)
                    if (acc[i][j][g] > thr) {
                        int t = atomicAdd(&rowcnt[rl], 1);
                        if (t < RCAP) {
                            rowlist[rl][t] = nb + j * 32 + ln31;
                            rowval[rl][t]  = acc[i][j][g];
                        }
                    }
            }
        __syncthreads();
    }

    // ---- E1: refilter vs final max, exact fp32 dot for keepers ----
    #pragma unroll 1
    for (int r = w; r < BQ; r += 8) {
        const int c = min(rowcnt[r], RCAP);
        const float thrf = rm_s[r] - MARGIN;
        #pragma unroll 1
        for (int t = 0; t < c; ++t) {
            const float av = rowval[r][t];
            if (av > thrf) {
                const int k = rowlist[r][t];
                const f32x4* qp = (const f32x4*)(Qb + (size_t)r * D_);
                const f32x4* mp = (const f32x4*)(Mb + (size_t)k * D_);
                float dot = 0.f;
                #pragma unroll
                for (int c4 = 0; c4 < 4; ++c4) {
                    f32x4 xv = qp[lane + 64 * c4];
                    f32x4 yv = mp[lane + 64 * c4];
                    dot += xv[0]*yv[0] + xv[1]*yv[1] + xv[2]*yv[2] + xv[3]*yv[3];
                }
                #pragma unroll
                for (int off = 32; off >= 1; off >>= 1)
                    dot += __shfl_xor(dot, off, 64);
                if (lane == 0) rowval[r][t] = dot;
            } else if (lane == 0) rowval[r][t] = -1e30f;
        }
    }
    __syncthreads();

    // ---- E2: exact softmax + PV per row ----
    #pragma unroll 1
    for (int r = w; r < BQ; r += 8) {
        const int c = min(rowcnt[r], RCAP);
        float mstar = -1e30f;
        for (int t = 0; t < c; ++t) mstar = fmaxf(mstar, rowval[r][t]);
        float denom = 0.f;
        f32x4 o[4];
        #pragma unroll
        for (int c4 = 0; c4 < 4; ++c4) o[c4] = (f32x4){0.f, 0.f, 0.f, 0.f};
        #pragma unroll 1
        for (int t = 0; t < c; ++t) {
            const float wgt = __expf(SCALE * (rowval[r][t] - mstar));
            if (wgt > 1e-22f) {
                denom += wgt;
                const f32x4* mp = (const f32x4*)(Mb + (size_t)rowlist[r][t] * D_);
                #pragma unroll
                for (int c4 = 0; c4 < 4; ++c4)
                    o[c4] += mp[lane + 64 * c4] * wgt;
            }
        }
        const float inv = 1.f / denom;
        f32x4* op = (f32x4*)(Out + ((size_t)b * L_ + q0 + r) * D_);
        #pragma unroll
        for (int c4 = 0; c4 < 4; ++c4) op[lane + 64 * c4] = o[c4] * inv;
    }
}

// ---------------- fallback (used only if ws too small): round-2 kernel ------
constexpr int FB_BKV = 256;
constexpr int FB_NKT = L_ / FB_BKV;
constexpr int FB_BD  = 32;
constexpr int FB_NDC = D_ / FB_BD;
constexpr int FB_STR = FB_BD + 8;
constexpr int FB_CAP = 2048;

__global__ __launch_bounds__(256) void attn_fb(
    const float* __restrict__ Q, const float* __restrict__ M,
    float* __restrict__ Out)
{
    __shared__ __bf16 qs[BQ * FB_STR];
    __shared__ __bf16 ms[FB_BKV * FB_STR];
    __shared__ float  wmax[4][BQ];
    __shared__ float  rowmax_s[BQ];
    __shared__ int    cnt_s;
    __shared__ int    list_s[FB_CAP];
    __shared__ float  elist_s[FB_CAP];

    const int b    = blockIdx.x & 7;
    const int qt   = blockIdx.x >> 3;
    const int q0   = qt * BQ;
    const int tid  = threadIdx.x;
    const int w    = tid >> 6;
    const int lane = tid & 63;
    const int ln15 = lane & 15;
    const int quad = lane >> 4;

    const float* Qb = Q + ((size_t)b * L_ + q0) * D_;
    const float* Mb = M + (size_t)b * L_ * D_;

    float rm[4][4];
    #pragma unroll
    for (int i = 0; i < 4; ++i)
        #pragma unroll
        for (int r = 0; r < 4; ++r) rm[i][r] = -INFINITY;

    #pragma unroll 1
    for (int pass = 0; pass < 2; ++pass) {
        #pragma unroll 1
        for (int kt = 0; kt < FB_NKT; ++kt) {
            f32x4 acc[4][4];
            #pragma unroll
            for (int i = 0; i < 4; ++i)
                #pragma unroll
                for (int j = 0; j < 4; ++j)
                    acc[i][j] = (f32x4){0.f, 0.f, 0.f, 0.f};
            const float* Mt = Mb + (size_t)(kt * FB_BKV) * D_;
            #pragma unroll 1
            for (int dc = 0; dc < FB_NDC; ++dc) {
                const int d0 = dc * FB_BD;
                __syncthreads();
                #pragma unroll
                for (int i = 0; i < 2; ++i) {
                    int f4 = tid + i * 256, row = f4 >> 3, c = f4 & 7;
                    float4 v = *(const float4*)(Qb + row * D_ + d0 + c * 4);
                    union { unsigned short h[4]; uint2 u; } t;
                    t.h[0] = f2bf(v.x); t.h[1] = f2bf(v.y);
                    t.h[2] = f2bf(v.z); t.h[3] = f2bf(v.w);
                    *(uint2*)(qs + row * FB_STR + c * 4) = t.u;
                }
                #pragma unroll
                for (int i = 0; i < 8; ++i) {
                    int f4 = tid + i * 256, row = f4 >> 3, c = f4 & 7;
                    float4 v = *(const float4*)(Mt + row * D_ + d0 + c * 4);
                    union { unsigned short h[4]; uint2 u; } t;
                    t.h[0] = f2bf(v.x); t.h[1] = f2bf(v.y);
                    t.h[2] = f2bf(v.z); t.h[3] = f2bf(v.w);
                    *(uint2*)(ms + row * FB_STR + c * 4) = t.u;
                }
                __syncthreads();
                bf16x8 afr[4], bfr[4];
                #pragma unroll
                for (int i = 0; i < 4; ++i)
                    afr[i] = *(const bf16x8*)(qs + (i * 16 + ln15) * FB_STR + quad * 8);
                #pragma unroll
                for (int j = 0; j < 4; ++j)
                    bfr[j] = *(const bf16x8*)(ms + (w * 64 + j * 16 + ln15) * FB_STR + quad * 8);
                #pragma unroll
                for (int i = 0; i < 4; ++i)
                    #pragma unroll
                    for (int j = 0; j < 4; ++j)
                        acc[i][j] = __builtin_amdgcn_mfma_f32_16x16x32_bf16(
                            afr[i], bfr[j], acc[i][j], 0, 0, 0);
            }
            if (pass == 0) {
                #pragma unroll
                for (int i = 0; i < 4; ++i)
                    #pragma unroll
                    for (int r = 0; r < 4; ++r) {
                        float m0 = fmaxf(fmaxf(acc[i][0][r], acc[i][1][r]),
                                         fmaxf(acc[i][2][r], acc[i][3][r]));
                        rm[i][r] = fmaxf(rm[i][r], m0);
                    }
            } else {
                #pragma unroll
                for (int i = 0; i < 4; ++i)
                    #pragma unroll
                    for (int j = 0; j < 4; ++j)
                        #pragma unroll
                        for (int r = 0; r < 4; ++r)
                            if (acc[i][j][r] > rm[i][r]) {
                                int idx = atomicAdd(&cnt_s, 1);
                                if (idx < FB_CAP)
                                    list_s[idx] = ((i * 16 + quad * 4 + r) << 16) |
                                                  (kt * FB_BKV + w * 64 + j * 16 + ln15);
                            }
            }
        }
        if (pass == 0) {
            #pragma unroll
            for (int i = 0; i < 4; ++i)
                #pragma unroll
                for (int r = 0; r < 4; ++r) {
                    float v = rm[i][r];
                    v = fmaxf(v, __shfl_xor(v, 1, 64));
                    v = fmaxf(v, __shfl_xor(v, 2, 64));
                    v = fmaxf(v, __shfl_xor(v, 4, 64));
                    v = fmaxf(v, __shfl_xor(v, 8, 64));
                    rm[i][r] = v;
                }
            if (ln15 == 0) {
                #pragma unroll
                for (int i = 0; i < 4; ++i)
                    #pragma unroll
                    for (int r = 0; r < 4; ++r)
                        wmax[w][i * 16 + quad * 4 + r] = rm[i][r];
            }
            __syncthreads();
            if (tid < BQ)
                rowmax_s[tid] = fmaxf(fmaxf(wmax[0][tid], wmax[1][tid]),
                                      fmaxf(wmax[2][tid], wmax[3][tid]));
            if (tid == 0) cnt_s = 0;
            __syncthreads();
            #pragma unroll
            for (int i = 0; i < 4; ++i)
                #pragma unroll
                for (int r = 0; r < 4; ++r)
                    rm[i][r] = rowmax_s[i * 16 + quad * 4 + r] - MARGIN;
        }
    }
    __syncthreads();
    const int n = min(cnt_s, FB_CAP);
    #pragma unroll 1
    for (int s = w; s < n; s += 4) {
        int e = list_s[s];
        int q = e >> 16, k = e & 0xFFFF;
        const float4* qp = (const float4*)(Qb + q * D_);
        const float4* mp = (const float4*)(Mb + (size_t)k * D_);
        float dot = 0.f;
        #pragma unroll
        for (int c = 0; c < 4; ++c) {
            float4 x = qp[lane + 64 * c];
            float4 y = mp[lane + 64 * c];
            dot += x.x * y.x + x.y * y.y + x.z * y.z + x.w * y.w;
        }
        #pragma unroll
        for (int off = 32; off >= 1; off >>= 1)
            dot += __shfl_xor(dot, off, 64);
        if (lane == 0) elist_s[s] = dot;
    }
    __syncthreads();
    #pragma unroll 1
    for (int r = w; r < BQ; r += 4) {
        float mstar = -INFINITY;
        for (int s = 0; s < n; ++s)
            if ((list_s[s] >> 16) == r) mstar = fmaxf(mstar, elist_s[s]);
        float denom = 0.f;
        f32x4 o[4];
        #pragma unroll
        for (int c = 0; c < 4; ++c) o[c] = (f32x4){0.f, 0.f, 0.f, 0.f};
        for (int s = 0; s < n; ++s) {
            if ((list_s[s] >> 16) != r) continue;
            float wgt = __expf(SCALE * (elist_s[s] - mstar));
            denom += wgt;
            const f32x4* mp = (const f32x4*)(Mb + (size_t)(list_s[s] & 0xFFFF) * D_);
            #pragma unroll
            for (int c = 0; c < 4; ++c) o[c] += mp[lane + 64 * c] * wgt;
        }
        const float inv = 1.f / denom;
        f32x4* op = (f32x4*)(Out + ((size_t)b * L_ + q0 + r) * D_);
        #pragma unroll
        for (int c = 0; c < 4; ++c) op[lane + 64 * c] = o[c] * inv;
    }
}

extern "C" void kernel_launch(void* const* d_in, const int* in_sizes, int n_in,
                              void* d_out, int out_size, void* d_ws, size_t ws_size,
                              hipStream_t stream)
{
    const float* Q = (const float*)d_in[0];
    const float* M = (const float*)d_in[1];
    float* Out = (float*)d_out;

    if (ws_size >= WS_NEED) {
        convert2<<<dim3(1024, 2), 256, 0, stream>>>(Q, M, (__bf16*)d_ws);
        attn_main<<<dim3(256), 512, 0, stream>>>(Q, M, (const __bf16*)d_ws, Out);
    } else {
        attn_fb<<<dim3(256), 256, 0, stream>>>(Q, M, Out);
    }
}